// Round 9
// baseline (2700.801 us; speedup 1.0000x reference)
//
#include <hip/hip_runtime.h>
#include <math.h>

#define BB 128
#define T2 2050
#define TT 2049
#define HH 64
#define GG 448   // 7*H
#define KK 100
#define NE 103   // K+3
#define NSTAGE 2056  // staged ev/dt length (TT + pipeline pad)
#define NTHREADS 640 // 10 waves: 8 gate + 2 logit

#define LOG2E 1.44269504088896340736f
#define LN2   0.69314718055994530942f

typedef float f32x4 __attribute__((ext_vector_type(4)));
typedef float f32x8 __attribute__((ext_vector_type(8)));

// ---- fast transcendentals (native v_exp_f32 / v_log_f32 / v_rcp_f32) ----
__device__ __forceinline__ float frcp(float x) { return __builtin_amdgcn_rcpf(x); }

__device__ __forceinline__ float sigmoid_fast(float x) {
    return frcp(1.f + exp2f(-x * LOG2E));
}
__device__ __forceinline__ float tanh_fast(float x) {
    float e = exp2f(x * (2.f * LOG2E));
    return 1.f - 2.f * frcp(1.f + e);
}
__device__ __forceinline__ float softplus_fast(float x) {
    float t = exp2f(-fabsf(x) * LOG2E);
    return fmaxf(x, 0.f) + LN2 * log2f(1.f + t);
}

// Sum over the 8 k8 row-groups (lanes differing in bits 3/4/5) entirely on
// the VALU — zero DS-pipe traffic:
//   xor8  : DPP row_ror:8 ((i+8)%16 == i^8 within each 16-row)
//   xor16 : v_permlane16_swap_b32   (HW-verified in R8: test passed)
//   xor32 : v_permlane32_swap_b32
__device__ __forceinline__ float ksum8(float v) {
    const int   b  = __builtin_bit_cast(int, v);
    const int   r  = __builtin_amdgcn_mov_dpp(b, 0x128, 0xf, 0xf, true);
    const float s8 = v + __builtin_bit_cast(float, r);
    float a = s8, b16 = s8;
    asm("v_permlane16_swap_b32 %0, %1" : "+v"(a), "+v"(b16));
    const float s16 = a + b16;
    float x = s16, y = s16;
    asm("v_permlane32_swap_b32 %0, %1" : "+v"(x), "+v"(y));
    return x + y;
}

__device__ __forceinline__ float dot8(const f32x4 h0, const f32x4 h1, const f32x8 w) {
    float a = h0.x * w[0];
    a = fmaf(h0.y, w[1], a);
    a = fmaf(h0.z, w[2], a);
    a = fmaf(h0.w, w[3], a);
    a = fmaf(h1.x, w[4], a);
    a = fmaf(h1.y, w[5], a);
    a = fmaf(h1.z, w[6], a);
    a = fmaf(h1.w, w[7], a);
    return a;
}

// pre_emb[e][t] = sum_k in_emb[e][k] * Wx[k][t] + bias[t]   (103 x 448)
__global__ void pre_emb_kernel(const float* __restrict__ in_emb,
                               const float* __restrict__ Wx,
                               const float* __restrict__ bias,
                               float* __restrict__ pre_emb) {
    int e = blockIdx.x;
    int t = threadIdx.x;
    float acc = bias[t];
#pragma unroll
    for (int k = 0; k < HH; ++k)
        acc = fmaf(in_emb[e * HH + k], Wx[k * GG + t], acc);
    pre_emb[e * GG + t] = acc;
}

// Raw barrier: fence LDS only (lgkmcnt); global loads/stores stay in flight.
__device__ __forceinline__ void step_barrier() {
    __builtin_amdgcn_sched_barrier(0);
    asm volatile("s_waitcnt lgkmcnt(0)" ::: "memory");
    __builtin_amdgcn_s_barrier();
    __builtin_amdgcn_sched_barrier(0);
}

// One block per batch row; 10 waves (8 gate + 2 logit), ONE lgkm barrier/step.
//  - gate wave w owns elements [8w, 8w+8); lane (k8=l>>3, c8=l&7) holds the
//    7 gate-columns of element 8w+c8 over k-slice [8k8, 8k8+8) as SEVEN
//    NAMED f32x8 vectors (56 VGPR — small/named so SROA promotes; the R7/R8
//    regressions were big per-lane arrays demoted to scratch, VGPR 80/120).
//    Per step: 2 ds_read_b128 (its 32B h-slice), 56 fmaf, 7 VALU ksum8,
//    acts + state (redundant over k8), lanes k8==0 publish h (one b32).
//    Gates are produced and consumed IN-WAVE: no gate exchange via LDS.
//  - logit waves (w=8,9) own 50 out_emb cols each (7 slots x 8k, slot 6
//    masked to c8<2), same reduce, softplus, store straight to out.
//  Per-step LDS: ~24 instrs vs ~112 in R6 (which was LDS-pipe bound).
__launch_bounds__(NTHREADS, 1)
__global__ void scan_kernel(const int* __restrict__ event,
                            const float* __restrict__ dtime,
                            const float* __restrict__ pre_emb,
                            const float* __restrict__ Wh,
                            const float* __restrict__ oe,
                            float* __restrict__ out) {
    const int b   = blockIdx.x;
    const int tid = threadIdx.x;
    const int w   = tid >> 6;     // wave 0..9
    const int l   = tid & 63;     // lane
    const int k8  = l >> 3;       // k-group 0..7
    const int c8  = l & 7;        // column slot 0..7

    __shared__ __align__(16) float hs[2][HH];   // double-buffered h
    __shared__ int   evoff_s[NSTAGE];           // pre_emb row offsets
    __shared__ float dtl_s[NSTAGE];

    const bool is_gate = (w < 8);
    const int  jw      = w - 8;                 // logit wave index 0..1
    const int  colb    = 8 * (w & 7) + c8;      // gate: owned element

    const int*   ev_row  = event + b * T2;
    const float* dt_row  = dtime + b * T2;
    float*       out_row = out + (size_t)b * TT * KK;

    // ---- stage ev (as row offsets) and dt into LDS (one-time) ----
    for (int i = tid; i < NSTAGE; i += NTHREADS) {
        const int idx = (i < T2) ? i : (T2 - 1);
        evoff_s[i] = ev_row[idx] * GG;
        dtl_s[i]   = dt_row[idx];
    }

    // ---- register-resident weights: NAMED f32x8 vectors only ----
    f32x8 wv0 = 0.f, wv1 = 0.f, wv2 = 0.f, wv3 = 0.f, wv4 = 0.f, wv5 = 0.f, wv6 = 0.f;
    if (is_gate) {
#define LOADG(W, g)                                                             \
        _Pragma("unroll") for (int kk = 0; kk < 8; ++kk)                        \
            W[kk] = Wh[(8 * k8 + kk) * GG + (g) * 64 + colb];
        LOADG(wv0, 0) LOADG(wv1, 1) LOADG(wv2, 2) LOADG(wv3, 3)
        LOADG(wv4, 4) LOADG(wv5, 5) LOADG(wv6, 6)
#undef LOADG
    } else {
#define LOADL(W, s)                                                             \
        {                                                                       \
            const int cc = (c8 + 8 * (s) < 50) ? (50 * jw + c8 + 8 * (s))       \
                                               : (50 * jw);                     \
            _Pragma("unroll") for (int kk = 0; kk < 8; ++kk)                    \
                W[kk] = oe[cc * HH + 8 * k8 + kk];                              \
        }
        LOADL(wv0, 0) LOADL(wv1, 1) LOADL(wv2, 2) LOADL(wv3, 3)
        LOADL(wv4, 4) LOADL(wv5, 5) LOADL(wv6, 6)
#undef LOADL
    }

    if (tid < HH) hs[0][tid] = 0.f;
    __syncthreads();   // evoff_s / dtl_s / hs[0] ready

    // ---- gate prologue: 2-step-deep pre/dt parity pipelines ----
    float preE[7], preO[7];
    int   offE = 0, offO = 0;
    float dtE = 0.f, dtO = 0.f;
    if (is_gate) {
        const int o0 = evoff_s[0], o1 = evoff_s[1];
#pragma unroll
        for (int g = 0; g < 7; ++g) {
            preE[g] = pre_emb[o0 + g * 64 + colb];   // pre_0 (used at t=0)
            preO[g] = pre_emb[o1 + g * 64 + colb];   // pre_1 (used at t=1)
        }
        offE = evoff_s[2];
        offO = evoff_s[3];
        dtE  = dtl_s[1];     // step t uses dt = dtime[t+1]
        dtO  = dtl_s[2];
    }

    float c = 0.f, cb = 0.f;

    // logit store bookkeeping: slot s -> col 50*jw + c8 + 8*s (s=6: c8<2)
    const int lc = 50 * jw + c8;
    float*    outP = out_row;

// ---- gate step t: h_{t-1} in hs[RB]; writes h_t to hs[WB] ----
#define GATE_STEP(RB, WB, PRE, OFF, DTV, TIDX)                                  \
    {                                                                           \
        float pu[7];                                                            \
        _Pragma("unroll") for (int g = 0; g < 7; ++g) pu[g] = PRE[g];           \
        const float* pb = pre_emb + OFF;                                        \
        _Pragma("unroll") for (int g = 0; g < 7; ++g) PRE[g] = pb[g * 64 + colb]; \
        OFF = evoff_s[(TIDX) + 4];                                              \
        const float dtu = DTV;                                                  \
        DTV = dtl_s[(TIDX) + 3];                                                \
        const f32x4* hp = (const f32x4*)&hs[RB][8 * k8];                        \
        const f32x4 h0 = hp[0], h1 = hp[1];                                     \
        const float gate0 = ksum8(dot8(h0, h1, wv0)) + pu[0];                   \
        const float gate1 = ksum8(dot8(h0, h1, wv1)) + pu[1];                   \
        const float gate2 = ksum8(dot8(h0, h1, wv2)) + pu[2];                   \
        const float gate3 = ksum8(dot8(h0, h1, wv3)) + pu[3];                   \
        const float gate4 = ksum8(dot8(h0, h1, wv4)) + pu[4];                   \
        const float gate5 = ksum8(dot8(h0, h1, wv5)) + pu[5];                   \
        const float gate6 = ksum8(dot8(h0, h1, wv6)) + pu[6];                   \
        const float ed  = exp2f(-dtu * log2f(1.f + exp2f(gate6 * LOG2E)));      \
        const float zg  = tanh_fast(gate2);                                     \
        const float ig  = sigmoid_fast(gate0);                                  \
        const float fg  = sigmoid_fast(gate1);                                  \
        const float ibg = sigmoid_fast(gate4);                                  \
        const float fbg = sigmoid_fast(gate5);                                  \
        const float og  = sigmoid_fast(gate3);                                  \
        const float ci  = fmaf(fg, c, ig * zg);                                 \
        const float cbi = fmaf(fbg, cb, ibg * zg);                              \
        const float cn  = fmaf(ci - cbi, ed, cbi);                              \
        const float h   = og * tanh_fast(cn);                                   \
        c  = cn;                                                                \
        cb = cbi;                                                               \
        if (k8 == 0) hs[WB][colb] = h;                                          \
    }

// ---- logit step: logits of h in hs[RB] -> row (outP); 1 step behind ----
#define LOGIT_STEP(RB, DO_STORE)                                                \
    {                                                                           \
        const f32x4* hp = (const f32x4*)&hs[RB][8 * k8];                        \
        const f32x4 h0 = hp[0], h1 = hp[1];                                     \
        const float r0 = ksum8(dot8(h0, h1, wv0));                              \
        const float r1 = ksum8(dot8(h0, h1, wv1));                              \
        const float r2 = ksum8(dot8(h0, h1, wv2));                              \
        const float r3 = ksum8(dot8(h0, h1, wv3));                              \
        const float r4 = ksum8(dot8(h0, h1, wv4));                              \
        const float r5 = ksum8(dot8(h0, h1, wv5));                              \
        const float r6 = ksum8(dot8(h0, h1, wv6));                              \
        if (DO_STORE) {                                                         \
            if (k8 == 0) {                                                      \
                outP[lc]      = softplus_fast(r0);                              \
                outP[lc + 8]  = softplus_fast(r1);                              \
                outP[lc + 16] = softplus_fast(r2);                              \
                outP[lc + 24] = softplus_fast(r3);                              \
                outP[lc + 32] = softplus_fast(r4);                              \
                outP[lc + 40] = softplus_fast(r5);                              \
                if (c8 < 2) outP[lc + 48] = softplus_fast(r6);                  \
            }                                                                   \
            outP += KK;                                                         \
        }                                                                       \
    }

    // main loop: 1024 double-steps cover t = 0..2047
    for (int tp = 0; tp < (TT - 1) / 2; ++tp) {
        const int te = 2 * tp;
        if (is_gate) { GATE_STEP(0, 1, preE, offE, dtE, te) }
        else         { LOGIT_STEP(0, (te > 0)) }      // h_{t-1}, t even
        step_barrier();
        if (is_gate) { GATE_STEP(1, 0, preO, offO, dtO, te + 1) }
        else         { LOGIT_STEP(1, true) }          // h_{t-1}, t odd
        step_barrier();
    }
    // tail step t = 2048 (even: read hs[0], write hs[1])
    if (is_gate) { GATE_STEP(0, 1, preE, offE, dtE, TT - 1) }
    else         { LOGIT_STEP(0, true) }              // row 2047
    step_barrier();

    // final logits: h_{2048} in hs[1] -> row 2048
    if (!is_gate) { LOGIT_STEP(1, true) }

#undef GATE_STEP
#undef LOGIT_STEP
}

extern "C" void kernel_launch(void* const* d_in, const int* in_sizes, int n_in,
                              void* d_out, int out_size, void* d_ws, size_t ws_size,
                              hipStream_t stream) {
    const int*   event  = (const int*)d_in[0];
    const float* dtime  = (const float*)d_in[1];
    const float* in_emb = (const float*)d_in[2];
    const float* Wx     = (const float*)d_in[3];
    const float* Wh     = (const float*)d_in[4];
    const float* bias   = (const float*)d_in[5];
    const float* oe     = (const float*)d_in[6];
    float*       out    = (float*)d_out;

    float* pre_emb = (float*)d_ws;  // 103*448*4 = 184,576 bytes

    pre_emb_kernel<<<NE, GG, 0, stream>>>(in_emb, Wx, bias, pre_emb);
    scan_kernel<<<BB, NTHREADS, 0, stream>>>(event, dtime, pre_emb, Wh, oe, out);
}